// Round 1
// baseline (707.762 us; speedup 1.0000x reference)
//
#include <hip/hip_runtime.h>
#include <math.h>

// Problem constants
#define BB 16
#define HH 56
#define WW 56
#define CC 256
#define C4 64
#define GG 8
#define O2 72
#define NPIX 50176   // B*H*W
#define HWP  3136    // H*W

// ---------------------------------------------------------------------------
// Generic 64x64 tiled fp32 GEMM: out[n,o] = sum_k Aload(n,k) * W[o*K+k] + bias[o]
// MODE 0: A plain
// MODE 1: A = relu(A*scale[k] + shift[k])   (BN+relu on load)   p0=scale p1=shift
// MODE 2: A = hw[n,k]*a0[b,k] + cm[n,k]*a1[b,k]                 p0=hw p1=cm p2=a0 p3=a1
// ---------------------------------------------------------------------------
template<int MODE>
__global__ __launch_bounds__(256) void gemm64(
    const float* __restrict__ A, const float* __restrict__ Wm,
    const float* __restrict__ bias, float* __restrict__ out,
    int N, int K, int O,
    const float* __restrict__ p0, const float* __restrict__ p1,
    const float* __restrict__ p2, const float* __restrict__ p3)
{
    __shared__ float As[64][17];
    __shared__ float Bs[16][65];
    const int tid = threadIdx.x;
    const int tx = tid & 15, ty = tid >> 4;
    const int rowBase = blockIdx.x * 64;
    const int ocBase  = blockIdx.y * 64;
    const int bb = rowBase / HWP;   // batch (valid: 3136 % 64 == 0)

    float acc[4][4] = {};

    for (int kc = 0; kc < K; kc += 16) {
        // ---- load A tile: 64 rows x 16 k
        #pragma unroll
        for (int i = 0; i < 4; ++i) {
            int e = i * 256 + tid;
            int r = e >> 4, kk = e & 15;
            int n = rowBase + r, k = kc + kk;
            float v;
            if constexpr (MODE == 0) {
                v = A[(size_t)n * K + k];
            } else if constexpr (MODE == 1) {
                v = fmaxf(A[(size_t)n * K + k] * p0[k] + p1[k], 0.f);
            } else {
                v = p0[(size_t)n * K + k] * p2[bb * K + k]
                  + p1[(size_t)n * K + k] * p3[bb * K + k];
            }
            As[r][kk] = v;
        }
        // ---- load B tile: Bs[k][o] = W[(ocBase+o)*K + kc + k]
        #pragma unroll
        for (int i = 0; i < 4; ++i) {
            int e = i * 256 + tid;
            int o = e >> 4, kk = e & 15;
            int oo = ocBase + o;
            Bs[kk][o] = (oo < O) ? Wm[(size_t)oo * K + kc + kk] : 0.f;
        }
        __syncthreads();
        #pragma unroll
        for (int k = 0; k < 16; ++k) {
            float ar[4], br[4];
            #pragma unroll
            for (int i = 0; i < 4; ++i) ar[i] = As[ty * 4 + i][k];
            #pragma unroll
            for (int j = 0; j < 4; ++j) br[j] = Bs[k][tx * 4 + j];
            #pragma unroll
            for (int i = 0; i < 4; ++i)
                #pragma unroll
                for (int j = 0; j < 4; ++j)
                    acc[i][j] = fmaf(ar[i], br[j], acc[i][j]);
        }
        __syncthreads();
    }

    #pragma unroll
    for (int i = 0; i < 4; ++i) {
        int n = rowBase + ty * 4 + i;
        #pragma unroll
        for (int j = 0; j < 4; ++j) {
            int oo = ocBase + tx * 4 + j;
            if (oo < O) {
                float bv = bias ? bias[oo] : 0.f;
                out[(size_t)n * O + oo] = acc[i][j] + bv;
            }
        }
    }
}

// ---------------------------------------------------------------------------
// BN batch stats over t [NPIX, 64]: per-channel sum & sumsq -> stats[0:64], stats[64:128]
// ---------------------------------------------------------------------------
__global__ __launch_bounds__(256) void bn_stats_kernel(
    const float* __restrict__ t, float* __restrict__ stats)
{
    __shared__ float ps[4][64], pq[4][64];
    const int tid = threadIdx.x;
    const int ch = tid & 63, rg = tid >> 6;
    const size_t base = (size_t)blockIdx.x * 512;
    float s = 0.f, q = 0.f;
    for (int r = rg; r < 512; r += 4) {
        float v = t[(base + r) * 64 + ch];
        s += v; q += v * v;
    }
    ps[rg][ch] = s; pq[rg][ch] = q;
    __syncthreads();
    if (rg == 0) {
        float ts = ps[0][ch] + ps[1][ch] + ps[2][ch] + ps[3][ch];
        float tq = pq[0][ch] + pq[1][ch] + pq[2][ch] + pq[3][ch];
        atomicAdd(&stats[ch], ts);
        atomicAdd(&stats[64 + ch], tq);
    }
}

__global__ void bn_finalize_kernel(
    const float* __restrict__ stats, const float* __restrict__ gamma,
    const float* __restrict__ beta, float* __restrict__ scsh)
{
    int ch = threadIdx.x;
    const float invN = 1.f / (float)NPIX;
    float mean = stats[ch] * invN;
    float var  = stats[64 + ch] * invN - mean * mean;
    float sc = gamma[ch] * rsqrtf(var + 1e-5f);
    scsh[ch] = sc;
    scsh[64 + ch] = beta[ch] - mean * sc;
}

// ---------------------------------------------------------------------------
// Involution: hw[n,c] = sum_{i,j} x[b,h+i-1,w+j-1,c] * wmat[n, g*9 + i*3+j]
// one block per (b,h); thread = channel
// ---------------------------------------------------------------------------
__global__ __launch_bounds__(256) void invol_kernel(
    const float* __restrict__ x, const float* __restrict__ wmat,
    float* __restrict__ hw)
{
    const int bh = blockIdx.x;               // b*56 + h
    const int b = bh / HH, h = bh % HH;
    const int c = threadIdx.x;
    const int g = c >> 5;
    for (int w = 0; w < WW; ++w) {
        const int n = bh * WW + w;
        const float* wr = wmat + (size_t)n * O2 + g * 9;
        float acc = 0.f;
        #pragma unroll
        for (int i = 0; i < 3; ++i) {
            int hh = h + i - 1;
            if (hh < 0 || hh >= HH) continue;
            #pragma unroll
            for (int j = 0; j < 3; ++j) {
                int ww = w + j - 1;
                if (ww < 0 || ww >= WW) continue;
                acc += x[((size_t)(b * HH + hh) * WW + ww) * CC + c] * wr[i * 3 + j];
            }
        }
        hw[(size_t)n * CC + c] = acc;
    }
}

// ---------------------------------------------------------------------------
// asum[b,c] += sum over pixel slice of (hw + cm)
// ---------------------------------------------------------------------------
__global__ __launch_bounds__(256) void mean_kernel(
    const float* __restrict__ hw, const float* __restrict__ cm,
    float* __restrict__ asum)
{
    const int b = blockIdx.x, s = blockIdx.y;
    const int c = threadIdx.x;
    const int base = b * HWP + s * (HWP / 8);
    float acc = 0.f;
    for (int p = 0; p < HWP / 8; ++p) {
        size_t idx = (size_t)(base + p) * CC + c;
        acc += hw[idx] + cm[idx];
    }
    atomicAdd(&asum[b * CC + c], acc);
}

// ---------------------------------------------------------------------------
// Gating MLP + pair softmax: one block per batch
// ---------------------------------------------------------------------------
__global__ __launch_bounds__(256) void mlp_kernel(
    const float* __restrict__ asum,
    const float* __restrict__ fc1_w, const float* __restrict__ fc1_b,
    const float* __restrict__ fc2_w, const float* __restrict__ fc2_b,
    float* __restrict__ a0, float* __restrict__ a1)
{
    __shared__ float a[256], hbuf[64], f[512];
    const int b = blockIdx.x, tid = threadIdx.x;
    a[tid] = asum[b * CC + tid] * (1.f / (float)HWP);
    __syncthreads();
    if (tid < 64) {
        float s = fc1_b[tid];
        for (int c = 0; c < 256; ++c) s += a[c] * fc1_w[tid * 256 + c];
        hbuf[tid] = 0.5f * s * (1.f + erff(s * 0.7071067811865476f));  // exact gelu
    }
    __syncthreads();
    for (int o = tid; o < 512; o += 256) {
        float s = fc2_b[o];
        for (int c = 0; c < 64; ++c) s += hbuf[c] * fc2_w[o * 64 + c];
        f[o] = s;
    }
    __syncthreads();
    float f0 = f[2 * tid], f1 = f[2 * tid + 1];
    float m = fmaxf(f0, f1);
    float e0 = expf(f0 - m), e1 = expf(f1 - m);
    float inv = 1.f / (e0 + e1);
    a0[b * CC + tid] = e0 * inv;
    a1[b * CC + tid] = e1 * inv;
}

// ---------------------------------------------------------------------------
extern "C" void kernel_launch(void* const* d_in, const int* in_sizes, int n_in,
                              void* d_out, int out_size, void* d_ws, size_t ws_size,
                              hipStream_t stream)
{
    (void)in_sizes; (void)n_in; (void)out_size; (void)ws_size;
    const float* x        = (const float*)d_in[0];
    const float* conv1_w  = (const float*)d_in[1];
    const float* conv1_b  = (const float*)d_in[2];
    const float* bn_gamma = (const float*)d_in[3];
    const float* bn_beta  = (const float*)d_in[4];
    const float* conv2_w  = (const float*)d_in[5];
    const float* conv2_b  = (const float*)d_in[6];
    const float* mlp_c_w  = (const float*)d_in[7];
    const float* fc1_w    = (const float*)d_in[8];
    const float* fc1_b    = (const float*)d_in[9];
    const float* fc2_w    = (const float*)d_in[10];
    const float* fc2_b    = (const float*)d_in[11];
    const float* projcnn_w= (const float*)d_in[12];
    const float* projcnn_b= (const float*)d_in[13];
    float* out = (float*)d_out;

    // Workspace layout (t and wmat alias the cm buffer: both dead before cm is written)
    float* ws   = (float*)d_ws;
    float* cm   = ws;                               // NPIX*256
    float* t    = ws;                               // NPIX*64   (inside cm region)
    float* wmat = ws + (size_t)NPIX * 64;           // NPIX*72   (inside cm region)
    float* hw   = ws + (size_t)NPIX * 256;          // NPIX*256
    float* stats= hw + (size_t)NPIX * 256;          // 128
    float* scsh = stats + 128;                      // 128
    float* asum = scsh + 128;                       // 16*256
    float* a0   = asum + BB * CC;                   // 16*256
    float* a1   = a0 + BB * CC;                     // 16*256

    hipMemsetAsync(stats, 0, (128 + 128 + BB * CC) * sizeof(float), stream);

    dim3 blk(256);
    // conv1: t = x @ conv1_w^T + b
    gemm64<0><<<dim3(784, 1), blk, 0, stream>>>(x, conv1_w, conv1_b, t,
        NPIX, 256, 64, nullptr, nullptr, nullptr, nullptr);
    // BN stats + finalize
    bn_stats_kernel<<<98, blk, 0, stream>>>(t, stats);
    bn_finalize_kernel<<<1, 64, 0, stream>>>(stats, bn_gamma, bn_beta, scsh);
    // conv2: wmat = relu(bn(t)) @ conv2_w^T + b
    gemm64<1><<<dim3(784, 2), blk, 0, stream>>>(t, conv2_w, conv2_b, wmat,
        NPIX, 64, O2, scsh, scsh + 64, nullptr, nullptr);
    // involution
    invol_kernel<<<BB * HH, blk, 0, stream>>>(x, wmat, hw);
    // mlp_c: cm = x @ mlp_c_w^T   (overwrites t/wmat region, both dead)
    gemm64<0><<<dim3(784, 4), blk, 0, stream>>>(x, mlp_c_w, nullptr, cm,
        NPIX, 256, 256, nullptr, nullptr, nullptr, nullptr);
    // pooled mean
    mean_kernel<<<dim3(BB, 8), blk, 0, stream>>>(hw, cm, asum);
    // gating MLP + pair softmax
    mlp_kernel<<<BB, blk, 0, stream>>>(asum, fc1_w, fc1_b, fc2_w, fc2_b, a0, a1);
    // final: out = (hw*a0 + cm*a1) @ projcnn_w^T + b
    gemm64<2><<<dim3(784, 4), blk, 0, stream>>>(nullptr, projcnn_w, projcnn_b, out,
        NPIX, 256, 256, hw, cm, a0, a1);
}

// Round 3
// 337.443 us; speedup vs baseline: 2.0974x; 2.0974x over previous
//
#include <hip/hip_runtime.h>
#include <math.h>

#define BB 16
#define HH 56
#define WW 56
#define CC 256
#define O2P 80          // conv2 output padded 72->80
#define NPIX 50176
#define HWP 3136

typedef __attribute__((ext_vector_type(4))) float f32x4;
typedef __attribute__((ext_vector_type(8))) short bh8;
typedef __attribute__((ext_vector_type(4))) short bh4;

__device__ inline short f2bf(float f) {
    union { float f; unsigned u; } v; v.f = f;
    unsigned r = (v.u + 0x7fffu + ((v.u >> 16) & 1u)) >> 16;
    return (short)r;
}
__device__ inline float bf2f(short s) {
    union { unsigned u; float f; } v; v.u = ((unsigned)(unsigned short)s) << 16;
    return v.f;
}

// ---------------------------------------------------------------------------
// Stage a [8*nchunks rows x 64 cols] bf16 tile into LDS via global_load_lds,
// source pre-swizzled so a swizzled ds_read (cb ^ (row&7)) sees global order.
// ---------------------------------------------------------------------------
__device__ inline void stage_tile(const short* __restrict__ src, int rowBase, int ldk,
                                  int kc, char* smem, int nchunks, int wid, int lane)
{
    for (int ci = wid; ci < nchunks; ci += 4) {
        int row = ci * 8 + (lane >> 3);
        int cb = (lane & 7) ^ (row & 7);
        const short* gp = src + (size_t)(rowBase + row) * ldk + kc + cb * 8;
        __builtin_amdgcn_global_load_lds(
            (const __attribute__((address_space(1))) void*)gp,
            (__attribute__((address_space(3))) void*)(smem + ci * 1024), 16, 0, 0);
    }
}

// ---------------------------------------------------------------------------
// MFMA GEMM: out[n,o] = sum_k A(n,k) * W[o,k] + bias[o]
// BM=128 rows/block, BK=64. AMODE 0: A bf16 direct (global_load_lds)
// AMODE 1: A fp32 + BN-scale/shift + relu -> bf16 (reg-staged)
// AMODE 2: A = hwb*a0[b] + cmb*a1[b] (bf16 pair blend, reg-staged)
// OUTBF: 0 = fp32 store, 1 = bf16 store
// ---------------------------------------------------------------------------
template<int BN, int AMODE, int OUTBF>
__global__ __launch_bounds__(256) void mgemm(
    const short* __restrict__ Ab,
    const float* __restrict__ Af, const float* __restrict__ scsh,
    const short* __restrict__ Ah, const short* __restrict__ Ac,
    const float* __restrict__ g0, const float* __restrict__ g1,
    const short* __restrict__ Wb, const float* __restrict__ bias,
    void* __restrict__ outp, int K, int O, int ldOut)
{
    constexpr int WN = (BN == 128) ? 2 : 1;
    constexpr int MR = (BN == 128) ? 4 : 2;
    constexpr int NR = BN / (16 * WN);
    constexpr int BCH = BN / 8;

    __shared__ alignas(16) char smA[16384];
    __shared__ alignas(16) char smB[BN * 128];

    const int tid = threadIdx.x;
    const int lane = tid & 63, wid = tid >> 6;
    const int rowBase = blockIdx.x * 128;
    const int ocBase = blockIdx.y * BN;
    const int waveM = (BN == 128) ? (wid >> 1) * 64 : wid * 32;
    const int waveN = (BN == 128) ? (wid & 1) * 64 : 0;

    f32x4 acc[MR][NR];
    #pragma unroll
    for (int m = 0; m < MR; ++m)
        #pragma unroll
        for (int n = 0; n < NR; ++n) acc[m][n] = f32x4{0.f, 0.f, 0.f, 0.f};

    for (int kc = 0; kc < K; kc += 64) {
        // ---- stage A tile (128 x 64 bf16)
        if constexpr (AMODE == 0) {
            stage_tile(Ab, rowBase, K, kc, smA, 16, wid, lane);
        } else if constexpr (AMODE == 1) {
            #pragma unroll
            for (int q = tid; q < 2048; q += 256) {          // float4 chunks
                int row = q >> 4, k4 = (q & 15) * 4;
                f32x4 v = *(const f32x4*)(Af + (size_t)(rowBase + row) * K + kc + k4);
                bh4 o;
                #pragma unroll
                for (int j = 0; j < 4; ++j) {
                    float sc = scsh[kc + k4 + j], sh = scsh[64 + kc + k4 + j];
                    o[j] = f2bf(fmaxf(v[j] * sc + sh, 0.f));
                }
                int byt = row * 128 + (((k4 >> 3) ^ (row & 7)) << 4) + (k4 & 7) * 2;
                *(bh4*)(smA + byt) = o;
            }
        } else {
            #pragma unroll
            for (int q = tid; q < 1024; q += 256) {          // 8-elem chunks
                int row = q >> 3, cb = q & 7;
                int n = rowBase + row;
                int b = n / HWP;
                const size_t off = (size_t)n * 256 + kc + cb * 8;
                bh8 h8 = *(const bh8*)(Ah + off);
                bh8 c8 = *(const bh8*)(Ac + off);
                bh8 o;
                #pragma unroll
                for (int j = 0; j < 8; ++j) {
                    float w0 = g0[b * 256 + kc + cb * 8 + j];
                    float w1 = g1[b * 256 + kc + cb * 8 + j];
                    o[j] = f2bf(bf2f(h8[j]) * w0 + bf2f(c8[j]) * w1);
                }
                *(bh8*)(smA + row * 128 + ((cb ^ (row & 7)) << 4)) = o;
            }
        }
        // ---- stage B tile (BN x 64 bf16)
        stage_tile(Wb, ocBase, K, kc, smB, BCH, wid, lane);
        __syncthreads();

        #pragma unroll
        for (int ks = 0; ks < 2; ++ks) {
            bh8 aF[MR], bF[NR];
            #pragma unroll
            for (int m = 0; m < MR; ++m) {
                int r = waveM + m * 16 + (lane & 15);
                int cb = ks * 4 + (lane >> 4);
                aF[m] = *(const bh8*)(smA + r * 128 + ((cb ^ (r & 7)) << 4));
            }
            #pragma unroll
            for (int n = 0; n < NR; ++n) {
                int r = waveN + n * 16 + (lane & 15);
                int cb = ks * 4 + (lane >> 4);
                bF[n] = *(const bh8*)(smB + r * 128 + ((cb ^ (r & 7)) << 4));
            }
            #pragma unroll
            for (int m = 0; m < MR; ++m)
                #pragma unroll
                for (int n = 0; n < NR; ++n)
                    acc[m][n] = __builtin_amdgcn_mfma_f32_16x16x32_bf16(
                        aF[m], bF[n], acc[m][n], 0, 0, 0);
        }
        __syncthreads();
    }

    #pragma unroll
    for (int m = 0; m < MR; ++m)
        #pragma unroll
        for (int n = 0; n < NR; ++n)
            #pragma unroll
            for (int j = 0; j < 4; ++j) {
                int r = rowBase + waveM + m * 16 + (lane >> 4) * 4 + j;
                int c = ocBase + waveN + n * 16 + (lane & 15);
                if (c < O) {
                    float v = acc[m][n][j] + (bias ? bias[c] : 0.f);
                    if constexpr (OUTBF)
                        ((short*)outp)[(size_t)r * ldOut + c] = f2bf(v);
                    else
                        ((float*)outp)[(size_t)r * ldOut + c] = v;
                }
            }
}

// ---------------------------------------------------------------------------
__global__ __launch_bounds__(256) void cvt_x_kernel(const float* __restrict__ x,
                                                    short* __restrict__ xb)
{
    size_t i = ((size_t)blockIdx.x * 256 + threadIdx.x) * 8;
    f32x4 v0 = *(const f32x4*)(x + i);
    f32x4 v1 = *(const f32x4*)(x + i + 4);
    bh8 o;
    #pragma unroll
    for (int j = 0; j < 4; ++j) { o[j] = f2bf(v0[j]); o[4 + j] = f2bf(v1[j]); }
    *(bh8*)(xb + i) = o;
}

__global__ __launch_bounds__(256) void cvt_w_kernel(
    const float* __restrict__ c1, const float* __restrict__ mc,
    const float* __restrict__ pj, const float* __restrict__ c2,
    short* __restrict__ c1b, short* __restrict__ mcb,
    short* __restrict__ pjb, short* __restrict__ c2b)
{
    int i = blockIdx.x * 256 + threadIdx.x;
    if (i < 16384) c1b[i] = f2bf(c1[i]);
    if (i < 65536) { mcb[i] = f2bf(mc[i]); pjb[i] = f2bf(pj[i]); }
    if (i < O2P * 64) {
        int o = i >> 6, k = i & 63;
        c2b[i] = (o < 72) ? f2bf(c2[o * 64 + k]) : (short)0;
    }
}

// ---------------------------------------------------------------------------
__global__ __launch_bounds__(256) void bn_stats_kernel(
    const float* __restrict__ t, float* __restrict__ stats)
{
    __shared__ float ps[4][64], pq[4][64];
    const int tid = threadIdx.x;
    const int ch = tid & 63, rg = tid >> 6;
    const size_t base = (size_t)blockIdx.x * 512;
    float s = 0.f, q = 0.f;
    for (int r = rg; r < 512; r += 4) {
        float v = t[(base + r) * 64 + ch];
        s += v; q += v * v;
    }
    ps[rg][ch] = s; pq[rg][ch] = q;
    __syncthreads();
    if (rg == 0) {
        atomicAdd(&stats[ch],      ps[0][ch] + ps[1][ch] + ps[2][ch] + ps[3][ch]);
        atomicAdd(&stats[64 + ch], pq[0][ch] + pq[1][ch] + pq[2][ch] + pq[3][ch]);
    }
}

__global__ void bn_finalize_kernel(
    const float* __restrict__ stats, const float* __restrict__ gamma,
    const float* __restrict__ beta, float* __restrict__ scsh)
{
    int ch = threadIdx.x;
    const float invN = 1.f / (float)NPIX;
    float mean = stats[ch] * invN;
    float var  = stats[64 + ch] * invN - mean * mean;
    float sc = gamma[ch] * rsqrtf(var + 1e-5f);
    scsh[ch] = sc;
    scsh[64 + ch] = beta[ch] - mean * sc;
}

// ---------------------------------------------------------------------------
// Involution with sliding-window x reuse; bf16 output.
// ---------------------------------------------------------------------------
__global__ __launch_bounds__(256) void invol_kernel(
    const float* __restrict__ x, const float* __restrict__ wmat,
    short* __restrict__ hwb)
{
    const int bh = blockIdx.x;
    const int b = bh / HH, h = bh % HH;
    const int c = threadIdx.x;
    const int g = c >> 5;
    const float* xb_ = x + (size_t)b * HWP * CC + c;

    float c0[3], c1[3], c2[3];
    auto loadcol = [&](int W, float* dst) {
        if (W < 0 || W >= WW) { dst[0] = dst[1] = dst[2] = 0.f; return; }
        #pragma unroll
        for (int i = 0; i < 3; ++i) {
            int hh = h + i - 1;
            dst[i] = (hh < 0 || hh >= HH) ? 0.f : xb_[((size_t)hh * WW + W) * CC];
        }
    };
    loadcol(-1, c0);
    loadcol(0, c1);
    for (int w = 0; w < WW; ++w) {
        loadcol(w + 1, c2);
        const int n = bh * WW + w;
        const float* wr = wmat + (size_t)n * O2P + g * 9;
        float acc = c0[0] * wr[0] + c1[0] * wr[1] + c2[0] * wr[2]
                  + c0[1] * wr[3] + c1[1] * wr[4] + c2[1] * wr[5]
                  + c0[2] * wr[6] + c1[2] * wr[7] + c2[2] * wr[8];
        hwb[(size_t)n * CC + c] = f2bf(acc);
        c0[0] = c1[0]; c0[1] = c1[1]; c0[2] = c1[2];
        c1[0] = c2[0]; c1[1] = c2[1]; c1[2] = c2[2];
    }
}

// ---------------------------------------------------------------------------
__global__ __launch_bounds__(256) void mean_kernel(
    const short* __restrict__ hwb, const short* __restrict__ cmb,
    float* __restrict__ asum)
{
    const int b = blockIdx.x, s = blockIdx.y;
    const int c = threadIdx.x;
    const int base = b * HWP + s * (HWP / 8);
    float acc = 0.f;
    for (int p = 0; p < HWP / 8; ++p) {
        size_t idx = (size_t)(base + p) * CC + c;
        acc += bf2f(hwb[idx]) + bf2f(cmb[idx]);
    }
    atomicAdd(&asum[b * CC + c], acc);
}

// ---------------------------------------------------------------------------
__global__ __launch_bounds__(256) void mlp_kernel(
    const float* __restrict__ asum,
    const float* __restrict__ fc1_w, const float* __restrict__ fc1_b,
    const float* __restrict__ fc2_w, const float* __restrict__ fc2_b,
    float* __restrict__ a0, float* __restrict__ a1)
{
    __shared__ float a[256], hbuf[64], f[512];
    const int b = blockIdx.x, tid = threadIdx.x;
    a[tid] = asum[b * CC + tid] * (1.f / (float)HWP);
    __syncthreads();
    if (tid < 64) {
        float s = fc1_b[tid];
        for (int c = 0; c < 256; ++c) s += a[c] * fc1_w[tid * 256 + c];
        hbuf[tid] = 0.5f * s * (1.f + erff(s * 0.7071067811865476f));
    }
    __syncthreads();
    for (int o = tid; o < 512; o += 256) {
        float s = fc2_b[o];
        for (int c = 0; c < 64; ++c) s += hbuf[c] * fc2_w[o * 64 + c];
        f[o] = s;
    }
    __syncthreads();
    float f0 = f[2 * tid], f1 = f[2 * tid + 1];
    float m = fmaxf(f0, f1);
    float e0 = expf(f0 - m), e1 = expf(f1 - m);
    float inv = 1.f / (e0 + e1);
    a0[b * CC + tid] = e0 * inv;
    a1[b * CC + tid] = e1 * inv;
}

// ---------------------------------------------------------------------------
extern "C" void kernel_launch(void* const* d_in, const int* in_sizes, int n_in,
                              void* d_out, int out_size, void* d_ws, size_t ws_size,
                              hipStream_t stream)
{
    (void)in_sizes; (void)n_in; (void)out_size; (void)ws_size;
    const float* x        = (const float*)d_in[0];
    const float* conv1_w  = (const float*)d_in[1];
    const float* conv1_b  = (const float*)d_in[2];
    const float* bn_gamma = (const float*)d_in[3];
    const float* bn_beta  = (const float*)d_in[4];
    const float* conv2_w  = (const float*)d_in[5];
    const float* conv2_b  = (const float*)d_in[6];
    const float* mlp_c_w  = (const float*)d_in[7];
    const float* fc1_w    = (const float*)d_in[8];
    const float* fc1_b    = (const float*)d_in[9];
    const float* fc2_w    = (const float*)d_in[10];
    const float* fc2_b    = (const float*)d_in[11];
    const float* projcnn_w= (const float*)d_in[12];
    const float* projcnn_b= (const float*)d_in[13];
    float* out = (float*)d_out;

    // workspace layout (bytes); t aliases cmb (t dead before cmb written)
    char* p = (char*)d_ws;
    short* xb  = (short*)p; p += (size_t)NPIX * 256 * 2;
    short* hwb = (short*)p; p += (size_t)NPIX * 256 * 2;
    short* cmb = (short*)p;
    float* t   = (float*)cmb;                 // NPIX*64*4 = 12.8MB <= 25.7MB
    p += (size_t)NPIX * 256 * 2;
    float* wmat = (float*)p; p += (size_t)NPIX * O2P * 4;
    short* c1b = (short*)p; p += 64 * 256 * 2;
    short* mcb = (short*)p; p += 256 * 256 * 2;
    short* pjb = (short*)p; p += 256 * 256 * 2;
    short* c2b = (short*)p; p += O2P * 64 * 2;
    float* stats = (float*)p; p += 128 * 4;
    float* asum  = (float*)p; p += BB * 256 * 4;
    float* scsh  = (float*)p; p += 128 * 4;
    float* a0    = (float*)p; p += BB * 256 * 4;
    float* a1    = (float*)p; p += BB * 256 * 4;

    hipMemsetAsync(stats, 0, (128 + BB * 256) * sizeof(float), stream);

    cvt_x_kernel<<<NPIX * 256 / (256 * 8), 256, 0, stream>>>(x, xb);
    cvt_w_kernel<<<256, 256, 0, stream>>>(conv1_w, mlp_c_w, projcnn_w, conv2_w,
                                          c1b, mcb, pjb, c2b);
    // conv1: t = xb @ conv1_w^T + b   [NPIX,64] fp32
    mgemm<64, 0, 0><<<dim3(392, 1), 256, 0, stream>>>(
        xb, nullptr, nullptr, nullptr, nullptr, nullptr, nullptr,
        c1b, conv1_b, t, 256, 64, 64);
    bn_stats_kernel<<<98, 256, 0, stream>>>(t, stats);
    bn_finalize_kernel<<<1, 64, 0, stream>>>(stats, bn_gamma, bn_beta, scsh);
    // conv2: wmat = relu(bn(t)) @ conv2_w^T + b   [NPIX,80] fp32 (72 valid)
    mgemm<O2P, 1, 0><<<dim3(392, 1), 256, 0, stream>>>(
        nullptr, t, scsh, nullptr, nullptr, nullptr, nullptr,
        c2b, conv2_b, wmat, 64, 72, O2P);
    invol_kernel<<<BB * HH, 256, 0, stream>>>(x, wmat, hwb);
    // mlp_c: cmb = xb @ mlp_c_w^T   [NPIX,256] bf16 (overwrites t, dead)
    mgemm<128, 0, 1><<<dim3(392, 2), 256, 0, stream>>>(
        xb, nullptr, nullptr, nullptr, nullptr, nullptr, nullptr,
        mcb, nullptr, cmb, 256, 256, 256);
    mean_kernel<<<dim3(BB, 8), 256, 0, stream>>>(hwb, cmb, asum);
    mlp_kernel<<<BB, 256, 0, stream>>>(asum, fc1_w, fc1_b, fc2_w, fc2_b, a0, a1);
    // final: out = (hwb*a0 + cmb*a1) @ projcnn_w^T + b
    mgemm<128, 2, 0><<<dim3(392, 2), 256, 0, stream>>>(
        nullptr, nullptr, nullptr, hwb, cmb, a0, a1,
        pjb, projcnn_b, out, 256, 256, 256);
}

// Round 4
// 296.354 us; speedup vs baseline: 2.3882x; 1.1386x over previous
//
#include <hip/hip_runtime.h>
#include <math.h>

#define BB 16
#define HH 56
#define WW 56
#define CC 256
#define O2P 80          // conv2 output padded 72->80
#define NPIX 50176
#define HWP 3136

typedef __attribute__((ext_vector_type(4))) float f32x4;
typedef __attribute__((ext_vector_type(8))) short bh8;
typedef __attribute__((ext_vector_type(4))) short bh4;

__device__ inline short f2bf(float f) {
    union { float f; unsigned u; } v; v.f = f;
    unsigned r = (v.u + 0x7fffu + ((v.u >> 16) & 1u)) >> 16;
    return (short)r;
}
__device__ inline float bf2f(short s) {
    union { unsigned u; float f; } v; v.u = ((unsigned)(unsigned short)s) << 16;
    return v.f;
}

// ---------------------------------------------------------------------------
// Stage a [8*nchunks rows x 64 cols] bf16 tile into LDS via global_load_lds,
// source pre-swizzled so a swizzled ds_read (cb ^ (row&7)) sees global order.
// ---------------------------------------------------------------------------
__device__ inline void stage_tile(const short* __restrict__ src, int rowBase, int ldk,
                                  int kc, char* smem, int nchunks, int wid, int lane)
{
    for (int ci = wid; ci < nchunks; ci += 4) {
        int row = ci * 8 + (lane >> 3);
        int cb = (lane & 7) ^ (row & 7);
        const short* gp = src + (size_t)(rowBase + row) * ldk + kc + cb * 8;
        __builtin_amdgcn_global_load_lds(
            (const __attribute__((address_space(1))) void*)gp,
            (__attribute__((address_space(3))) void*)(smem + ci * 1024), 16, 0, 0);
    }
}

// ---------------------------------------------------------------------------
// MFMA GEMM: out[n,o] = sum_k A(n,k) * W[o,k] + bias[o]
// BM=128 rows/block, BK=64. AMODE 0: A bf16 direct (global_load_lds)
// AMODE 1: A bf16 t + BN-scale/shift + relu (reg-staged)
// AMODE 2: A = hwb*a0[b] + cmb*a1[b] (bf16 pair blend, reg-staged)
// OUTBF: 0 = fp32 store, 1 = bf16 store
// ---------------------------------------------------------------------------
template<int BN, int AMODE, int OUTBF>
__global__ __launch_bounds__(256) void mgemm(
    const short* __restrict__ Ab,
    const short* __restrict__ At, const float* __restrict__ scsh,
    const short* __restrict__ Ah, const short* __restrict__ Ac,
    const float* __restrict__ g0, const float* __restrict__ g1,
    const short* __restrict__ Wb, const float* __restrict__ bias,
    void* __restrict__ outp, int K, int O, int ldOut)
{
    constexpr int WN = (BN == 128) ? 2 : 1;
    constexpr int MR = (BN == 128) ? 4 : 2;
    constexpr int NR = BN / (16 * WN);
    constexpr int BCH = BN / 8;

    __shared__ alignas(16) char smA[16384];
    __shared__ alignas(16) char smB[BN * 128];

    const int tid = threadIdx.x;
    const int lane = tid & 63, wid = tid >> 6;
    const int rowBase = blockIdx.x * 128;
    const int ocBase = blockIdx.y * BN;
    const int waveM = (BN == 128) ? (wid >> 1) * 64 : wid * 32;
    const int waveN = (BN == 128) ? (wid & 1) * 64 : 0;

    f32x4 acc[MR][NR];
    #pragma unroll
    for (int m = 0; m < MR; ++m)
        #pragma unroll
        for (int n = 0; n < NR; ++n) acc[m][n] = f32x4{0.f, 0.f, 0.f, 0.f};

    for (int kc = 0; kc < K; kc += 64) {
        // ---- stage A tile (128 x 64 bf16)
        if constexpr (AMODE == 0) {
            stage_tile(Ab, rowBase, K, kc, smA, 16, wid, lane);
        } else if constexpr (AMODE == 1) {
            #pragma unroll
            for (int q = tid; q < 1024; q += 256) {          // bh8 chunks of bf16 t
                int row = q >> 3, cb = q & 7;
                bh8 v = *(const bh8*)(At + (size_t)(rowBase + row) * K + kc + cb * 8);
                bh8 o;
                #pragma unroll
                for (int j = 0; j < 8; ++j) {
                    int k = kc + cb * 8 + j;
                    o[j] = f2bf(fmaxf(bf2f(v[j]) * scsh[k] + scsh[64 + k], 0.f));
                }
                *(bh8*)(smA + row * 128 + ((cb ^ (row & 7)) << 4)) = o;
            }
        } else {
            #pragma unroll
            for (int q = tid; q < 1024; q += 256) {          // 8-elem chunks
                int row = q >> 3, cb = q & 7;
                int n = rowBase + row;
                int b = n / HWP;
                const size_t off = (size_t)n * 256 + kc + cb * 8;
                bh8 h8 = *(const bh8*)(Ah + off);
                bh8 c8 = *(const bh8*)(Ac + off);
                bh8 o;
                #pragma unroll
                for (int j = 0; j < 8; ++j) {
                    float w0 = g0[b * 256 + kc + cb * 8 + j];
                    float w1 = g1[b * 256 + kc + cb * 8 + j];
                    o[j] = f2bf(bf2f(h8[j]) * w0 + bf2f(c8[j]) * w1);
                }
                *(bh8*)(smA + row * 128 + ((cb ^ (row & 7)) << 4)) = o;
            }
        }
        // ---- stage B tile (BN x 64 bf16)
        stage_tile(Wb, ocBase, K, kc, smB, BCH, wid, lane);
        __syncthreads();

        #pragma unroll
        for (int ks = 0; ks < 2; ++ks) {
            bh8 aF[MR], bF[NR];
            #pragma unroll
            for (int m = 0; m < MR; ++m) {
                int r = waveM + m * 16 + (lane & 15);
                int cb = ks * 4 + (lane >> 4);
                aF[m] = *(const bh8*)(smA + r * 128 + ((cb ^ (r & 7)) << 4));
            }
            #pragma unroll
            for (int n = 0; n < NR; ++n) {
                int r = waveN + n * 16 + (lane & 15);
                int cb = ks * 4 + (lane >> 4);
                bF[n] = *(const bh8*)(smB + r * 128 + ((cb ^ (r & 7)) << 4));
            }
            #pragma unroll
            for (int m = 0; m < MR; ++m)
                #pragma unroll
                for (int n = 0; n < NR; ++n)
                    acc[m][n] = __builtin_amdgcn_mfma_f32_16x16x32_bf16(
                        aF[m], bF[n], acc[m][n], 0, 0, 0);
        }
        __syncthreads();
    }

    #pragma unroll
    for (int m = 0; m < MR; ++m)
        #pragma unroll
        for (int n = 0; n < NR; ++n)
            #pragma unroll
            for (int j = 0; j < 4; ++j) {
                int r = rowBase + waveM + m * 16 + (lane >> 4) * 4 + j;
                int c = ocBase + waveN + n * 16 + (lane & 15);
                if (c < O) {
                    float v = acc[m][n][j] + (bias ? bias[c] : 0.f);
                    if constexpr (OUTBF)
                        ((short*)outp)[(size_t)r * ldOut + c] = f2bf(v);
                    else
                        ((float*)outp)[(size_t)r * ldOut + c] = v;
                }
            }
}

// ---------------------------------------------------------------------------
// x fp32 -> bf16, fused per-batch channel sums sxb[b][c] (for analytic mean(c))
// Block: 256 threads x 8 elems = 8 pixels (b-uniform since 3136 % 8 == 0)
// ---------------------------------------------------------------------------
__global__ __launch_bounds__(256) void cvt_x_kernel(const float* __restrict__ x,
                                                    short* __restrict__ xb,
                                                    float* __restrict__ sxb)
{
    __shared__ float sm[8][256];
    const int tid = threadIdx.x;
    size_t base = (size_t)blockIdx.x * 2048 + tid * 8;
    const int b = (int)(base >> 8) / HWP;
    const int ch0 = (int)(base & 255);
    const int pix = (tid * 8) >> 8;           // 0..7 within block

    f32x4 v0 = *(const f32x4*)(x + base);
    f32x4 v1 = *(const f32x4*)(x + base + 4);
    bh8 o;
    #pragma unroll
    for (int j = 0; j < 4; ++j) { o[j] = f2bf(v0[j]); o[4 + j] = f2bf(v1[j]); }
    *(bh8*)(xb + base) = o;

    #pragma unroll
    for (int j = 0; j < 4; ++j) {
        sm[pix][ch0 + j] = v0[j];
        sm[pix][ch0 + 4 + j] = v1[j];
    }
    __syncthreads();
    float s = 0.f;
    #pragma unroll
    for (int p = 0; p < 8; ++p) s += sm[p][tid];
    atomicAdd(&sxb[b * CC + tid], s);
}

__global__ __launch_bounds__(256) void cvt_w_kernel(
    const float* __restrict__ c1, const float* __restrict__ mc,
    const float* __restrict__ pj, const float* __restrict__ c2,
    short* __restrict__ c1b, short* __restrict__ mcb,
    short* __restrict__ pjb, short* __restrict__ c2b)
{
    int i = blockIdx.x * 256 + threadIdx.x;
    if (i < 16384) c1b[i] = f2bf(c1[i]);
    if (i < 65536) { mcb[i] = f2bf(mc[i]); pjb[i] = f2bf(pj[i]); }
    if (i < O2P * 64) {
        int o = i >> 6, k = i & 63;
        c2b[i] = (o < 72) ? f2bf(c2[o * 64 + k]) : (short)0;
    }
}

// ---------------------------------------------------------------------------
// BN batch stats over bf16 t [NPIX,64], vectorized bh8 loads + LDS reduce
// ---------------------------------------------------------------------------
__global__ __launch_bounds__(256) void bn_stats_kernel(
    const short* __restrict__ t, float* __restrict__ stats)
{
    __shared__ float ss[32][64], sq[32][64];
    const int tid = threadIdx.x;
    const int grp = tid >> 3, ch0 = (tid & 7) * 8;
    const size_t rowBase = (size_t)blockIdx.x * 512;
    float s[8] = {}, q[8] = {};
    for (int r = grp; r < 512; r += 32) {
        bh8 v = *(const bh8*)(t + (rowBase + r) * 64 + ch0);
        #pragma unroll
        for (int j = 0; j < 8; ++j) {
            float f = bf2f(v[j]);
            s[j] += f; q[j] += f * f;
        }
    }
    #pragma unroll
    for (int j = 0; j < 8; ++j) { ss[grp][ch0 + j] = s[j]; sq[grp][ch0 + j] = q[j]; }
    __syncthreads();
    if (tid < 64) {
        float ts = 0.f, tq = 0.f;
        #pragma unroll
        for (int g = 0; g < 32; ++g) { ts += ss[g][tid]; tq += sq[g][tid]; }
        atomicAdd(&stats[tid], ts);
        atomicAdd(&stats[64 + tid], tq);
    }
}

__global__ void bn_finalize_kernel(
    const float* __restrict__ stats, const float* __restrict__ gamma,
    const float* __restrict__ beta, float* __restrict__ scsh)
{
    int ch = threadIdx.x;
    const float invN = 1.f / (float)NPIX;
    float mean = stats[ch] * invN;
    float var  = stats[64 + ch] * invN - mean * mean;
    float sc = gamma[ch] * rsqrtf(var + 1e-5f);
    scsh[ch] = sc;
    scsh[64 + ch] = beta[ch] - mean * sc;
}

// ---------------------------------------------------------------------------
// Involution v2: bf16 x + bf16 wmat, 4 ch/lane, W-split x2, fused hw-mean.
// Block: 256 thr = 4 waves; wave handles 7 w-columns, lane handles 4 channels.
// ---------------------------------------------------------------------------
__global__ __launch_bounds__(256) void invol_kernel(
    const short* __restrict__ xb, const short* __restrict__ wmatb,
    short* __restrict__ hwb, float* __restrict__ asum)
{
    __shared__ float sm4[4][256];
    const int idx = blockIdx.x;
    const int s = idx & 1, bh = idx >> 1;
    const int b = bh / HH, h = bh % HH;
    const int tid = threadIdx.x;
    const int lane = tid & 63, wid = tid >> 6;
    const int c4 = lane * 4;
    const int g = lane >> 3;
    const int w0 = s * 28 + wid * 7;
    const short* xbase = xb + ((size_t)b * HWP) * CC + c4;

    float cL[3][4], cM[3][4], cR[3][4];
    auto loadcol = [&](int Wc, float d[3][4]) {
        #pragma unroll
        for (int i = 0; i < 3; ++i) {
            int hh = h + i - 1;
            if (Wc < 0 || Wc >= WW || hh < 0 || hh >= HH) {
                d[i][0] = d[i][1] = d[i][2] = d[i][3] = 0.f;
            } else {
                bh4 v = *(const bh4*)(xbase + (size_t)(hh * WW + Wc) * CC);
                #pragma unroll
                for (int j = 0; j < 4; ++j) d[i][j] = bf2f(v[j]);
            }
        }
    };
    loadcol(w0 - 1, cL);
    loadcol(w0, cM);

    float loc[4] = {0.f, 0.f, 0.f, 0.f};
    for (int w = w0; w < w0 + 7; ++w) {
        loadcol(w + 1, cR);
        const int n = bh * WW + w;
        const short* wr = wmatb + (size_t)n * O2P + g * 9;
        float wf[9];
        #pragma unroll
        for (int t9 = 0; t9 < 9; ++t9) wf[t9] = bf2f(wr[t9]);
        bh4 ov;
        #pragma unroll
        for (int j = 0; j < 4; ++j) {
            float a = cL[0][j] * wf[0] + cM[0][j] * wf[1] + cR[0][j] * wf[2]
                    + cL[1][j] * wf[3] + cM[1][j] * wf[4] + cR[1][j] * wf[5]
                    + cL[2][j] * wf[6] + cM[2][j] * wf[7] + cR[2][j] * wf[8];
            loc[j] += a;
            ov[j] = f2bf(a);
        }
        *(bh4*)(hwb + (size_t)n * CC + c4) = ov;
        #pragma unroll
        for (int i = 0; i < 3; ++i)
            #pragma unroll
            for (int j = 0; j < 4; ++j) { cL[i][j] = cM[i][j]; cM[i][j] = cR[i][j]; }
    }
    #pragma unroll
    for (int j = 0; j < 4; ++j) sm4[wid][c4 + j] = loc[j];
    __syncthreads();
    float tot = sm4[0][tid] + sm4[1][tid] + sm4[2][tid] + sm4[3][tid];
    atomicAdd(&asum[b * CC + tid], tot);
}

// ---------------------------------------------------------------------------
// Gating MLP: analytic mean(c) from sxb @ mlp_c_w^T, + fused softmax pair
// ---------------------------------------------------------------------------
__global__ __launch_bounds__(256) void mlp_kernel(
    const float* __restrict__ asum, const float* __restrict__ sxb,
    const float* __restrict__ mlp_c_w,
    const float* __restrict__ fc1_w, const float* __restrict__ fc1_b,
    const float* __restrict__ fc2_w, const float* __restrict__ fc2_b,
    float* __restrict__ a0, float* __restrict__ a1)
{
    __shared__ float a[256], hbuf[64], f[512];
    const int b = blockIdx.x, tid = threadIdx.x;
    // analytic cm channel-sum: sum_pix(cm)[o] = sum_c sxb[b,c]*W[o,c]
    float acm = 0.f;
    const float* wrow = mlp_c_w + (size_t)tid * 256;
    for (int c = 0; c < 256; ++c) acm += sxb[b * CC + c] * wrow[c];
    a[tid] = (asum[b * CC + tid] + acm) * (1.f / (float)HWP);
    __syncthreads();
    if (tid < 64) {
        float s = fc1_b[tid];
        for (int c = 0; c < 256; ++c) s += a[c] * fc1_w[tid * 256 + c];
        hbuf[tid] = 0.5f * s * (1.f + erff(s * 0.7071067811865476f));
    }
    __syncthreads();
    for (int o = tid; o < 512; o += 256) {
        float s = fc2_b[o];
        for (int c = 0; c < 64; ++c) s += hbuf[c] * fc2_w[o * 64 + c];
        f[o] = s;
    }
    __syncthreads();
    float f0 = f[2 * tid], f1 = f[2 * tid + 1];
    float m = fmaxf(f0, f1);
    float e0 = expf(f0 - m), e1 = expf(f1 - m);
    float inv = 1.f / (e0 + e1);
    a0[b * CC + tid] = e0 * inv;
    a1[b * CC + tid] = e1 * inv;
}

// ---------------------------------------------------------------------------
extern "C" void kernel_launch(void* const* d_in, const int* in_sizes, int n_in,
                              void* d_out, int out_size, void* d_ws, size_t ws_size,
                              hipStream_t stream)
{
    (void)in_sizes; (void)n_in; (void)out_size; (void)ws_size;
    const float* x        = (const float*)d_in[0];
    const float* conv1_w  = (const float*)d_in[1];
    const float* conv1_b  = (const float*)d_in[2];
    const float* bn_gamma = (const float*)d_in[3];
    const float* bn_beta  = (const float*)d_in[4];
    const float* conv2_w  = (const float*)d_in[5];
    const float* conv2_b  = (const float*)d_in[6];
    const float* mlp_c_w  = (const float*)d_in[7];
    const float* fc1_w    = (const float*)d_in[8];
    const float* fc1_b    = (const float*)d_in[9];
    const float* fc2_w    = (const float*)d_in[10];
    const float* fc2_b    = (const float*)d_in[11];
    const float* projcnn_w= (const float*)d_in[12];
    const float* projcnn_b= (const float*)d_in[13];
    float* out = (float*)d_out;

    // workspace layout; t aliases cmb (t dead before cmb written)
    char* p = (char*)d_ws;
    short* xb  = (short*)p; p += (size_t)NPIX * 256 * 2;
    short* hwb = (short*)p; p += (size_t)NPIX * 256 * 2;
    short* cmb = (short*)p;
    short* t   = (short*)cmb;                 // NPIX*64*2 = 6.4MB <= 25.7MB
    p += (size_t)NPIX * 256 * 2;
    short* wmatb = (short*)p; p += (size_t)NPIX * O2P * 2;
    short* c1b = (short*)p; p += 64 * 256 * 2;
    short* mcb = (short*)p; p += 256 * 256 * 2;
    short* pjb = (short*)p; p += 256 * 256 * 2;
    short* c2b = (short*)p; p += O2P * 64 * 2;
    float* stats = (float*)p; p += 128 * 4;
    float* asum  = (float*)p; p += BB * 256 * 4;   // hw pixel-sums
    float* sxb   = (float*)p; p += BB * 256 * 4;   // x pixel-sums (fp32)
    float* scsh  = (float*)p; p += 128 * 4;
    float* a0    = (float*)p; p += BB * 256 * 4;
    float* a1    = (float*)p; p += BB * 256 * 4;

    hipMemsetAsync(stats, 0, (128 + 2 * BB * 256) * sizeof(float), stream);

    cvt_x_kernel<<<NPIX * 256 / 2048, 256, 0, stream>>>(x, xb, sxb);
    cvt_w_kernel<<<256, 256, 0, stream>>>(conv1_w, mlp_c_w, projcnn_w, conv2_w,
                                          c1b, mcb, pjb, c2b);
    // conv1: t = xb @ conv1_w^T + b   [NPIX,64] bf16
    mgemm<64, 0, 1><<<dim3(392, 1), 256, 0, stream>>>(
        xb, nullptr, nullptr, nullptr, nullptr, nullptr, nullptr,
        c1b, conv1_b, t, 256, 64, 64);
    bn_stats_kernel<<<98, 256, 0, stream>>>(t, stats);
    bn_finalize_kernel<<<1, 64, 0, stream>>>(stats, bn_gamma, bn_beta, scsh);
    // conv2: wmatb = relu(bn(t)) @ conv2_w^T + b   [NPIX,80] bf16 (72 valid)
    mgemm<O2P, 1, 1><<<dim3(392, 1), 256, 0, stream>>>(
        nullptr, t, scsh, nullptr, nullptr, nullptr, nullptr,
        c2b, conv2_b, wmatb, 64, 72, O2P);
    // involution (fused hw pixel-sum)
    invol_kernel<<<BB * HH * 2, 256, 0, stream>>>(xb, wmatb, hwb, asum);
    // mlp_c: cmb = xb @ mlp_c_w^T   [NPIX,256] bf16 (overwrites t, dead)
    mgemm<128, 0, 1><<<dim3(392, 2), 256, 0, stream>>>(
        xb, nullptr, nullptr, nullptr, nullptr, nullptr, nullptr,
        mcb, nullptr, cmb, 256, 256, 256);
    // gating MLP (+ analytic mean(c))
    mlp_kernel<<<BB, 256, 0, stream>>>(asum, sxb, mlp_c_w,
                                       fc1_w, fc1_b, fc2_w, fc2_b, a0, a1);
    // final: out = (hwb*a0 + cmb*a1) @ projcnn_w^T + b
    mgemm<128, 2, 0><<<dim3(392, 2), 256, 0, stream>>>(
        nullptr, nullptr, nullptr, hwb, cmb, a0, a1,
        pjb, projcnn_b, out, 256, 256, 256);
}

// Round 5
// 281.997 us; speedup vs baseline: 2.5098x; 1.0509x over previous
//
#include <hip/hip_runtime.h>
#include <math.h>

#define BB 16
#define HH 56
#define WW 56
#define CC 256
#define O2P 80          // conv2 output padded 72->80
#define NPIX 50176
#define HWP 3136

typedef __attribute__((ext_vector_type(4))) float f32x4;
typedef __attribute__((ext_vector_type(8))) short bh8;
typedef __attribute__((ext_vector_type(4))) short bh4;

__device__ inline short f2bf(float f) {
    union { float f; unsigned u; } v; v.f = f;
    unsigned r = (v.u + 0x7fffu + ((v.u >> 16) & 1u)) >> 16;
    return (short)r;
}
__device__ inline float bf2f(short s) {
    union { unsigned u; float f; } v; v.u = ((unsigned)(unsigned short)s) << 16;
    return v.f;
}

// ---------------------------------------------------------------------------
// Stage a [8*nchunks rows x 64 cols] bf16 tile into LDS via global_load_lds,
// source pre-swizzled so a swizzled ds_read (cb ^ (row&7)) sees global order.
// ---------------------------------------------------------------------------
__device__ inline void stage_tile(const short* __restrict__ src, int rowBase, int ldk,
                                  int kc, char* smem, int nchunks, int wid, int lane)
{
    for (int ci = wid; ci < nchunks; ci += 4) {
        int row = ci * 8 + (lane >> 3);
        int cb = (lane & 7) ^ (row & 7);
        const short* gp = src + (size_t)(rowBase + row) * ldk + kc + cb * 8;
        __builtin_amdgcn_global_load_lds(
            (const __attribute__((address_space(1))) void*)gp,
            (__attribute__((address_space(3))) void*)(smem + ci * 1024), 16, 0, 0);
    }
}

// ---------------------------------------------------------------------------
// MFMA GEMM, BM=64 rows/block, BK=64.
// AMODE 0: A bf16 direct (global_load_lds)
// AMODE 1: A bf16 + BN-scale/shift + relu (reg-staged)          [conv2]
// AMODE 3: A = concat[Ab | A2] (each ld 256), W per-batch fold  [proj]
// OUTBF: 0 = fp32 store, 1 = bf16 store
// ---------------------------------------------------------------------------
template<int BN, int AMODE, int OUTBF>
__global__ __launch_bounds__(256) void mgemm64(
    const short* __restrict__ Ab, const short* __restrict__ A2,
    const float* __restrict__ scsh,
    const short* __restrict__ Wb, const float* __restrict__ bias,
    void* __restrict__ outp, int K, int O, int ldOut)
{
    constexpr int MR = (BN == 80) ? 1 : 2;
    constexpr int NR = (BN == 80) ? 5 : (BN == 128 ? 4 : 2);
    constexpr int BCH = BN / 8;

    __shared__ alignas(16) char smA[8192];
    __shared__ alignas(16) char smB[BN * 128];

    const int tid = threadIdx.x;
    const int lane = tid & 63, wid = tid >> 6;
    const int rowBase = blockIdx.x * 64;
    const int ocBase = blockIdx.y * BN;
    const int waveM = (BN == 80) ? wid * 16 : (wid & 1) * 32;
    const int waveN = (BN == 80) ? 0 : (BN == 128 ? (wid >> 1) * 64 : (wid >> 1) * 32);

    const short* wptr = Wb;
    if constexpr (AMODE == 3)
        wptr += (size_t)(rowBase / HWP) * 256 * 512;   // per-batch folded W

    f32x4 acc[MR][NR];
    #pragma unroll
    for (int m = 0; m < MR; ++m)
        #pragma unroll
        for (int n = 0; n < NR; ++n) acc[m][n] = f32x4{0.f, 0.f, 0.f, 0.f};

    for (int kc = 0; kc < K; kc += 64) {
        // ---- stage A tile (64 x 64 bf16)
        if constexpr (AMODE == 0) {
            stage_tile(Ab, rowBase, K, kc, smA, 8, wid, lane);
        } else if constexpr (AMODE == 3) {
            const short* s = (kc < 256) ? Ab : A2;
            stage_tile(s, rowBase, 256, kc & 255, smA, 8, wid, lane);
        } else {
            #pragma unroll
            for (int q = tid; q < 512; q += 256) {           // bh8 chunks of bf16 A
                int row = q >> 3, cb = q & 7;
                bh8 v = *(const bh8*)(Ab + (size_t)(rowBase + row) * K + kc + cb * 8);
                bh8 o;
                #pragma unroll
                for (int j = 0; j < 8; ++j) {
                    int k = kc + cb * 8 + j;
                    o[j] = f2bf(fmaxf(bf2f(v[j]) * scsh[k] + scsh[64 + k], 0.f));
                }
                *(bh8*)(smA + row * 128 + ((cb ^ (row & 7)) << 4)) = o;
            }
        }
        // ---- stage B tile (BN x 64 bf16)
        stage_tile(wptr, ocBase, K, kc, smB, BCH, wid, lane);
        __syncthreads();

        #pragma unroll
        for (int ks = 0; ks < 2; ++ks) {
            bh8 aF[MR], bF[NR];
            #pragma unroll
            for (int m = 0; m < MR; ++m) {
                int r = waveM + m * 16 + (lane & 15);
                int cb = ks * 4 + (lane >> 4);
                aF[m] = *(const bh8*)(smA + r * 128 + ((cb ^ (r & 7)) << 4));
            }
            #pragma unroll
            for (int n = 0; n < NR; ++n) {
                int r = waveN + n * 16 + (lane & 15);
                int cb = ks * 4 + (lane >> 4);
                bF[n] = *(const bh8*)(smB + r * 128 + ((cb ^ (r & 7)) << 4));
            }
            #pragma unroll
            for (int m = 0; m < MR; ++m)
                #pragma unroll
                for (int n = 0; n < NR; ++n)
                    acc[m][n] = __builtin_amdgcn_mfma_f32_16x16x32_bf16(
                        aF[m], bF[n], acc[m][n], 0, 0, 0);
        }
        __syncthreads();
    }

    #pragma unroll
    for (int m = 0; m < MR; ++m)
        #pragma unroll
        for (int n = 0; n < NR; ++n)
            #pragma unroll
            for (int j = 0; j < 4; ++j) {
                int r = rowBase + waveM + m * 16 + (lane >> 4) * 4 + j;
                int c = ocBase + waveN + n * 16 + (lane & 15);
                if (c < O) {
                    float v = acc[m][n][j] + (bias ? bias[c] : 0.f);
                    if constexpr (OUTBF)
                        ((short*)outp)[(size_t)r * ldOut + c] = f2bf(v);
                    else
                        ((float*)outp)[(size_t)r * ldOut + c] = v;
                }
            }
}

// ---------------------------------------------------------------------------
// x fp32 -> bf16, fused per-batch channel sums sxb[b][c] (for analytic mean(c))
// ---------------------------------------------------------------------------
__global__ __launch_bounds__(256) void cvt_x_kernel(const float* __restrict__ x,
                                                    short* __restrict__ xb,
                                                    float* __restrict__ sxb)
{
    __shared__ float sm[8][256];
    const int tid = threadIdx.x;
    size_t base = (size_t)blockIdx.x * 2048 + tid * 8;
    const int b = (int)(base >> 8) / HWP;
    const int ch0 = (int)(base & 255);
    const int pix = (tid * 8) >> 8;

    f32x4 v0 = *(const f32x4*)(x + base);
    f32x4 v1 = *(const f32x4*)(x + base + 4);
    bh8 o;
    #pragma unroll
    for (int j = 0; j < 4; ++j) { o[j] = f2bf(v0[j]); o[4 + j] = f2bf(v1[j]); }
    *(bh8*)(xb + base) = o;

    #pragma unroll
    for (int j = 0; j < 4; ++j) {
        sm[pix][ch0 + j] = v0[j];
        sm[pix][ch0 + 4 + j] = v1[j];
    }
    __syncthreads();
    float s = 0.f;
    #pragma unroll
    for (int p = 0; p < 8; ++p) s += sm[p][tid];
    atomicAdd(&sxb[b * CC + tid], s);
}

__global__ __launch_bounds__(256) void cvt_w_kernel(
    const float* __restrict__ c1, const float* __restrict__ mc,
    const float* __restrict__ c2,
    short* __restrict__ c1b, short* __restrict__ mcb, short* __restrict__ c2b)
{
    int i = blockIdx.x * 256 + threadIdx.x;
    if (i < 16384) c1b[i] = f2bf(c1[i]);
    if (i < 65536) mcb[i] = f2bf(mc[i]);
    if (i < O2P * 64) {
        int o = i >> 6, k = i & 63;
        c2b[i] = (o < 72) ? f2bf(c2[o * 64 + k]) : (short)0;
    }
}

// ---------------------------------------------------------------------------
// Per-batch folded proj weights: wf[b][o][k'] = W[o,k]*a0/a1[b,k]
// ---------------------------------------------------------------------------
__global__ __launch_bounds__(256) void fold_w_kernel(
    const float* __restrict__ pjw, const float* __restrict__ a0,
    const float* __restrict__ a1, short* __restrict__ wf)
{
    size_t base = ((size_t)blockIdx.x * 256 + threadIdx.x) * 8;   // 2M elems /8
    int b = (int)(base >> 17);
    int rem = (int)(base & 131071);
    int o = rem >> 9, k0 = rem & 511;
    const float* av = (k0 < 256) ? (a0 + b * 256 + k0) : (a1 + b * 256 + k0 - 256);
    const float* wrow = pjw + o * 256 + (k0 & 255);
    bh8 ov;
    #pragma unroll
    for (int j = 0; j < 8; ++j) ov[j] = f2bf(wrow[j] * av[j]);
    *(bh8*)(wf + base) = ov;
}

// ---------------------------------------------------------------------------
// BN batch stats over bf16 t [NPIX,64]
// ---------------------------------------------------------------------------
__global__ __launch_bounds__(256) void bn_stats_kernel(
    const short* __restrict__ t, float* __restrict__ stats)
{
    __shared__ float ss[32][64], sq[32][64];
    const int tid = threadIdx.x;
    const int grp = tid >> 3, ch0 = (tid & 7) * 8;
    const size_t rowBase = (size_t)blockIdx.x * 512;
    float s[8] = {}, q[8] = {};
    for (int r = grp; r < 512; r += 32) {
        bh8 v = *(const bh8*)(t + (rowBase + r) * 64 + ch0);
        #pragma unroll
        for (int j = 0; j < 8; ++j) {
            float f = bf2f(v[j]);
            s[j] += f; q[j] += f * f;
        }
    }
    #pragma unroll
    for (int j = 0; j < 8; ++j) { ss[grp][ch0 + j] = s[j]; sq[grp][ch0 + j] = q[j]; }
    __syncthreads();
    if (tid < 64) {
        float ts = 0.f, tq = 0.f;
        #pragma unroll
        for (int g = 0; g < 32; ++g) { ts += ss[g][tid]; tq += sq[g][tid]; }
        atomicAdd(&stats[tid], ts);
        atomicAdd(&stats[64 + tid], tq);
    }
}

__global__ void bn_finalize_kernel(
    const float* __restrict__ stats, const float* __restrict__ gamma,
    const float* __restrict__ beta, float* __restrict__ scsh)
{
    int ch = threadIdx.x;
    const float invN = 1.f / (float)NPIX;
    float mean = stats[ch] * invN;
    float var  = stats[64 + ch] * invN - mean * mean;
    float sc = gamma[ch] * rsqrtf(var + 1e-5f);
    scsh[ch] = sc;
    scsh[64 + ch] = beta[ch] - mean * sc;
}

// ---------------------------------------------------------------------------
// Involution: bf16 x + bf16 wmat, 4 ch/lane, W-split x2, fused hw pixel-sum.
// ---------------------------------------------------------------------------
__global__ __launch_bounds__(256) void invol_kernel(
    const short* __restrict__ xb, const short* __restrict__ wmatb,
    short* __restrict__ hwb, float* __restrict__ asum)
{
    __shared__ float sm4[4][256];
    const int idx = blockIdx.x;
    const int s = idx & 1, bh = idx >> 1;
    const int b = bh / HH, h = bh % HH;
    const int tid = threadIdx.x;
    const int lane = tid & 63, wid = tid >> 6;
    const int c4 = lane * 4;
    const int g = lane >> 3;
    const int w0 = s * 28 + wid * 7;
    const short* xbase = xb + ((size_t)b * HWP) * CC + c4;

    float cL[3][4], cM[3][4], cR[3][4];
    auto loadcol = [&](int Wc, float d[3][4]) {
        #pragma unroll
        for (int i = 0; i < 3; ++i) {
            int hh = h + i - 1;
            if (Wc < 0 || Wc >= WW || hh < 0 || hh >= HH) {
                d[i][0] = d[i][1] = d[i][2] = d[i][3] = 0.f;
            } else {
                bh4 v = *(const bh4*)(xbase + (size_t)(hh * WW + Wc) * CC);
                #pragma unroll
                for (int j = 0; j < 4; ++j) d[i][j] = bf2f(v[j]);
            }
        }
    };
    loadcol(w0 - 1, cL);
    loadcol(w0, cM);

    float loc[4] = {0.f, 0.f, 0.f, 0.f};
    for (int w = w0; w < w0 + 7; ++w) {
        loadcol(w + 1, cR);
        const int n = bh * WW + w;
        const short* wr = wmatb + (size_t)n * O2P + g * 9;
        float wf[9];
        #pragma unroll
        for (int t9 = 0; t9 < 9; ++t9) wf[t9] = bf2f(wr[t9]);
        bh4 ov;
        #pragma unroll
        for (int j = 0; j < 4; ++j) {
            float a = cL[0][j] * wf[0] + cM[0][j] * wf[1] + cR[0][j] * wf[2]
                    + cL[1][j] * wf[3] + cM[1][j] * wf[4] + cR[1][j] * wf[5]
                    + cL[2][j] * wf[6] + cM[2][j] * wf[7] + cR[2][j] * wf[8];
            loc[j] += a;
            ov[j] = f2bf(a);
        }
        *(bh4*)(hwb + (size_t)n * CC + c4) = ov;
        #pragma unroll
        for (int i = 0; i < 3; ++i)
            #pragma unroll
            for (int j = 0; j < 4; ++j) { cL[i][j] = cM[i][j]; cM[i][j] = cR[i][j]; }
    }
    #pragma unroll
    for (int j = 0; j < 4; ++j) sm4[wid][c4 + j] = loc[j];
    __syncthreads();
    float tot = sm4[0][tid] + sm4[1][tid] + sm4[2][tid] + sm4[3][tid];
    atomicAdd(&asum[b * CC + tid], tot);
}

// ---------------------------------------------------------------------------
// Gating MLP: analytic mean(c) from sxb @ mlp_c_w^T, + softmax pair
// ---------------------------------------------------------------------------
__global__ __launch_bounds__(256) void mlp_kernel(
    const float* __restrict__ asum, const float* __restrict__ sxb,
    const float* __restrict__ mlp_c_w,
    const float* __restrict__ fc1_w, const float* __restrict__ fc1_b,
    const float* __restrict__ fc2_w, const float* __restrict__ fc2_b,
    float* __restrict__ a0, float* __restrict__ a1)
{
    __shared__ float a[256], hbuf[64], f[512];
    const int b = blockIdx.x, tid = threadIdx.x;
    float acm = 0.f;
    {
        const f32x4* w4 = (const f32x4*)(mlp_c_w + (size_t)tid * 256);
        const f32x4* s4 = (const f32x4*)(sxb + b * CC);
        for (int c = 0; c < 64; ++c) {
            f32x4 sv = s4[c], wv = w4[c];
            acm += sv[0] * wv[0] + sv[1] * wv[1] + sv[2] * wv[2] + sv[3] * wv[3];
        }
    }
    a[tid] = (asum[b * CC + tid] + acm) * (1.f / (float)HWP);
    __syncthreads();
    if (tid < 64) {
        float s = fc1_b[tid];
        const f32x4* w4 = (const f32x4*)(fc1_w + (size_t)tid * 256);
        const f32x4* a4 = (const f32x4*)a;
        for (int c = 0; c < 64; ++c) {
            f32x4 av = a4[c], wv = w4[c];
            s += av[0] * wv[0] + av[1] * wv[1] + av[2] * wv[2] + av[3] * wv[3];
        }
        hbuf[tid] = 0.5f * s * (1.f + erff(s * 0.7071067811865476f));
    }
    __syncthreads();
    for (int o = tid; o < 512; o += 256) {
        float s = fc2_b[o];
        const f32x4* w4 = (const f32x4*)(fc2_w + (size_t)o * 64);
        const f32x4* h4 = (const f32x4*)hbuf;
        #pragma unroll
        for (int c = 0; c < 16; ++c) {
            f32x4 hv = h4[c], wv = w4[c];
            s += hv[0] * wv[0] + hv[1] * wv[1] + hv[2] * wv[2] + hv[3] * wv[3];
        }
        f[o] = s;
    }
    __syncthreads();
    float f0 = f[2 * tid], f1 = f[2 * tid + 1];
    float m = fmaxf(f0, f1);
    float e0 = expf(f0 - m), e1 = expf(f1 - m);
    float inv = 1.f / (e0 + e1);
    a0[b * CC + tid] = e0 * inv;
    a1[b * CC + tid] = e1 * inv;
}

// ---------------------------------------------------------------------------
extern "C" void kernel_launch(void* const* d_in, const int* in_sizes, int n_in,
                              void* d_out, int out_size, void* d_ws, size_t ws_size,
                              hipStream_t stream)
{
    (void)in_sizes; (void)n_in; (void)out_size; (void)ws_size;
    const float* x        = (const float*)d_in[0];
    const float* conv1_w  = (const float*)d_in[1];
    const float* conv1_b  = (const float*)d_in[2];
    const float* bn_gamma = (const float*)d_in[3];
    const float* bn_beta  = (const float*)d_in[4];
    const float* conv2_w  = (const float*)d_in[5];
    const float* conv2_b  = (const float*)d_in[6];
    const float* mlp_c_w  = (const float*)d_in[7];
    const float* fc1_w    = (const float*)d_in[8];
    const float* fc1_b    = (const float*)d_in[9];
    const float* fc2_w    = (const float*)d_in[10];
    const float* fc2_b    = (const float*)d_in[11];
    const float* projcnn_w= (const float*)d_in[12];
    const float* projcnn_b= (const float*)d_in[13];
    float* out = (float*)d_out;

    // workspace layout; t aliases cmb (t dead before cmb written)
    char* p = (char*)d_ws;
    short* xb  = (short*)p; p += (size_t)NPIX * 256 * 2;
    short* hwb = (short*)p; p += (size_t)NPIX * 256 * 2;
    short* cmb = (short*)p;
    short* t   = (short*)cmb;                 // NPIX*64*2 inside cmb
    p += (size_t)NPIX * 256 * 2;
    short* wmatb = (short*)p; p += (size_t)NPIX * O2P * 2;
    short* wfold = (short*)p; p += (size_t)BB * 256 * 512 * 2;  // 4MB
    short* c1b = (short*)p; p += 64 * 256 * 2;
    short* mcb = (short*)p; p += 256 * 256 * 2;
    short* c2b = (short*)p; p += O2P * 64 * 2;
    float* stats = (float*)p; p += 128 * 4;
    float* asum  = (float*)p; p += BB * 256 * 4;
    float* sxb   = (float*)p; p += BB * 256 * 4;
    float* scsh  = (float*)p; p += 128 * 4;
    float* a0    = (float*)p; p += BB * 256 * 4;
    float* a1    = (float*)p; p += BB * 256 * 4;

    hipMemsetAsync(stats, 0, (128 + 2 * BB * 256) * sizeof(float), stream);

    cvt_x_kernel<<<NPIX * 256 / 2048, 256, 0, stream>>>(x, xb, sxb);
    cvt_w_kernel<<<256, 256, 0, stream>>>(conv1_w, mlp_c_w, conv2_w, c1b, mcb, c2b);
    // conv1: t = xb @ conv1_w^T + b   [NPIX,64] bf16
    mgemm64<64, 0, 1><<<dim3(784, 1), 256, 0, stream>>>(
        xb, nullptr, nullptr, c1b, conv1_b, t, 256, 64, 64);
    bn_stats_kernel<<<98, 256, 0, stream>>>(t, stats);
    bn_finalize_kernel<<<1, 64, 0, stream>>>(stats, bn_gamma, bn_beta, scsh);
    // conv2: wmatb = relu(bn(t)) @ conv2_w^T + b   [NPIX,80] bf16 (72 valid)
    mgemm64<O2P, 1, 1><<<dim3(784, 1), 256, 0, stream>>>(
        t, nullptr, scsh, c2b, conv2_b, wmatb, 64, 72, O2P);
    // involution (fused hw pixel-sum)
    invol_kernel<<<BB * HH * 2, 256, 0, stream>>>(xb, wmatb, hwb, asum);
    // mlp_c: cmb = xb @ mlp_c_w^T   [NPIX,256] bf16
    mgemm64<128, 0, 1><<<dim3(784, 2), 256, 0, stream>>>(
        xb, nullptr, nullptr, mcb, nullptr, cmb, 256, 256, 256);
    // gating MLP (+ analytic mean(c))
    mlp_kernel<<<BB, 256, 0, stream>>>(asum, sxb, mlp_c_w,
                                       fc1_w, fc1_b, fc2_w, fc2_b, a0, a1);
    // fold gating into proj weights per batch
    fold_w_kernel<<<1024, 256, 0, stream>>>(projcnn_w, a0, a1, wfold);
    // final: out = [hwb|cmb] @ wfold_b^T + bias   (K=512, pure MFMA path)
    mgemm64<128, 3, 0><<<dim3(784, 2), 256, 0, stream>>>(
        hwb, cmb, nullptr, wfold, projcnn_b, out, 512, 256, 256);
}